// Round 15
// baseline (147.070 us; speedup 1.0000x reference)
//
#include <hip/hip_runtime.h>
#include <stdint.h>

#define B_DIM 16384
#define L_DIM 4096
#define H_DIM 256
#define LN_EPS 1e-5f

typedef unsigned short u16;
typedef __attribute__((ext_vector_type(4))) float f32x4;
typedef __attribute__((ext_vector_type(8))) short short8;

__device__ __forceinline__ u16 f2bf(float f) {
  union { float f; uint32_t u; } v; v.f = f;
  uint32_t u = v.u;
  u += 0x7FFFu + ((u >> 16) & 1u);   // round-to-nearest-even
  return (u16)(u >> 16);
}

__device__ __forceinline__ short8 cvt8(const float4& u, const float4& v) {
  short8 o;
  o[0] = (short)f2bf(u.x); o[1] = (short)f2bf(u.y);
  o[2] = (short)f2bf(u.z); o[3] = (short)f2bf(u.w);
  o[4] = (short)f2bf(v.x); o[5] = (short)f2bf(v.y);
  o[6] = (short)f2bf(v.z); o[7] = (short)f2bf(v.w);
  return o;
}

__device__ __forceinline__ void gload_lds16(const void* g, void* l) {
  __builtin_amdgcn_global_load_lds((const __attribute__((address_space(1))) void*)g,
                                   (__attribute__((address_space(3))) void*)l, 16, 0, 0);
}

// Fragment-major prep (gathered emb / plain W1):
// frag = kstep*16 + nt;  dst[frag][lane][j] = bf16(src[row][nt*16 + (lane&15)])
// row = idx ? idx[kstep*32 + (lane>>4)*8 + j] : (kstep*32 + (lane>>4)*8 + j)
__global__ __launch_bounds__(256) void prep_frag(const float* __restrict__ src,
                                                 const int* __restrict__ idx,
                                                 u16* __restrict__ dst) {
  const int t = threadIdx.x;
  const int l = t & 63;
  const int w = t >> 6;
  const int frag = blockIdx.x * 4 + w;
  const int kstep = frag >> 4;
  const int nt = frag & 15;
  const int n = nt * 16 + (l & 15);
  const int kbase = kstep * 32 + (l >> 4) * 8;
  short8 v;
#pragma unroll
  for (int j = 0; j < 8; ++j) {
    const int k = kbase + j;
    const int g = idx ? idx[k] : k;
    v[j] = (short)f2bf(src[(size_t)g * H_DIM + n]);
  }
  *reinterpret_cast<short8*>(dst + ((size_t)frag * 64 + l) * 8) = v;
}

// Fused: h = x @ feat (bf16 MFMA, K=4096), then out = LN(relu(h @ W1 + b1)).
// R15: DEEP PIPELINE (T3+T4). All previous rounds were 2-phase drain-to-0
// schedules and all landed ~95us fused regardless of stage content (R7..R14)
// -- the m233 "2-phase ~72% overhead" signature. This kernel: half-tile =
// one kstep (K=32), 4-slot LDS ring for A (4x4KB, x f32, pre-swizzled src /
// swizzled read) and B (4x16KB fragment-major linear). Per iteration (128):
// ONE barrier, counted vmcnt(10) (2 half-tiles stay in flight -- NEVER
// drain-0 in the loop; tail peels 10->5->0), issue slot h+3, compute h.
// Overwrite safety: slot h-1 rewritten only after the h-barrier, reached
// only after each wave's h-1 ds_reads drained (lgkm0 + sched_barrier, #18).
// All staging is gload_lds (no dest reg -> no hidden compiler vmcnt waits).
// BM=32, 4-wave blocks, LDS 80KB -> 2 blocks/CU, grid 512.
__global__ __launch_bounds__(256, 2) void fused(const float* __restrict__ x,
                                                const u16* __restrict__ fragB,
                                                const u16* __restrict__ fragW,
                                                const float* __restrict__ b1,
                                                const float* __restrict__ gmm,
                                                const float* __restrict__ bta,
                                                float* __restrict__ out) {
  // main: B slots 4x16KB @0; A slots 4x4KB @65536.  gemm2 (time-separated):
  // h-tile 16KB @0, W dbuf 2x16KB @16384, lnred 2KB @49152.
  __shared__ __align__(16) char pool[81920];
  const int t = threadIdx.x;
  const int l = t & 63;
  const int wv = t >> 6;                 // 0..3 : col group (64 cols)
  const int m0 = blockIdx.x * 32;

  // A staging (1 gload_lds/wave/half-tile): wave wv stages rows wv*8..wv*8+7.
  // Lane l lands at LDS row R = wv*8 + (l>>3), 16B-slot s = l&7; source chunk
  // is pre-swizzled c = s ^ (R&7) so the compute read (chunk c at slot
  // c^(row&7)) is conflict-free (8 distinct bank-quads per 8 rows, 2-way).
  const int R = wv * 8 + (l >> 3);
  const int c = (l & 7) ^ (R & 7);
  const float* asrc = x + (size_t)(m0 + R) * L_DIM + c * 4;

  f32x4 acc[2][4] = {};

  // ---- prologue: issue half-tiles 0,1,2 (order pinned: 5 ops each) ----
#pragma unroll
  for (int hn = 0; hn < 3; ++hn) {
#pragma unroll
    for (int i = 0; i < 4; ++i) {
      const int fr = wv * 4 + i;
      gload_lds16(fragB + ((size_t)(hn * 16 + fr)) * 512 + l * 8,
                  pool + hn * 16384 + fr * 1024);
    }
    gload_lds16(asrc + hn * 32, pool + 65536 + hn * 4096 + wv * 1024);
    __builtin_amdgcn_sched_barrier(0);
  }

  auto issue = [&](int hn) {                       // 5 gload_lds for half-tile hn
    char* Bd = pool + (hn & 3) * 16384;
#pragma unroll
    for (int i = 0; i < 4; ++i) {
      const int fr = wv * 4 + i;
      gload_lds16(fragB + ((size_t)(hn * 16 + fr)) * 512 + l * 8, Bd + fr * 1024);
    }
    gload_lds16(asrc + hn * 32, pool + 65536 + (hn & 3) * 4096 + wv * 1024);
  };

  auto compute = [&](int h) {
    const char* Ab = pool + 65536 + (h & 3) * 4096;
    const char* Bb = pool + (h & 3) * 16384;
    short8 af[2];
#pragma unroll
    for (int mi = 0; mi < 2; ++mi) {
      const int row = mi * 16 + (l & 15);
      const int c0 = (l >> 4) * 2;
      const float4 a0 = *(const float4*)(Ab + row * 128 + ((c0 ^ (row & 7)) * 16));
      const float4 a1 = *(const float4*)(Ab + row * 128 + (((c0 + 1) ^ (row & 7)) * 16));
      af[mi] = cvt8(a0, a1);
    }
#pragma unroll
    for (int ni = 0; ni < 4; ++ni) {
      const short8 bf = *(const short8*)(Bb + (wv * 4 + ni) * 1024 + l * 16);
#pragma unroll
      for (int mi = 0; mi < 2; ++mi)
        acc[mi][ni] = __builtin_amdgcn_mfma_f32_16x16x32_bf16(af[mi], bf, acc[mi][ni], 0, 0, 0);
    }
    // own ds_reads drained before next barrier (so slot h-1 rewrite is safe)
    asm volatile("s_waitcnt lgkmcnt(0)" ::: "memory");
    __builtin_amdgcn_sched_barrier(0);             // rule #18: fence after lgkm
  };

  // steady: at top of h, queue = [h:5, h+1:5, h+2:5] -> vmcnt(10) drains h only
  for (int h = 0; h < 125; ++h) {
    asm volatile("s_waitcnt vmcnt(10)" ::: "memory");
    __builtin_amdgcn_s_barrier();
    __builtin_amdgcn_sched_barrier(0);
    issue(h + 3);
    __builtin_amdgcn_sched_barrier(0);
    compute(h);
  }
  asm volatile("s_waitcnt vmcnt(10)" ::: "memory"); // h=125: [125,126,127]
  __builtin_amdgcn_s_barrier();
  __builtin_amdgcn_sched_barrier(0);
  compute(125);
  asm volatile("s_waitcnt vmcnt(5)" ::: "memory");  // h=126: [126,127]
  __builtin_amdgcn_s_barrier();
  __builtin_amdgcn_sched_barrier(0);
  compute(126);
  asm volatile("s_waitcnt vmcnt(0)" ::: "memory");  // h=127
  __builtin_amdgcn_s_barrier();
  __builtin_amdgcn_sched_barrier(0);
  compute(127);

  // ---- GEMM2 (verbatim from the 106us passing kernel): issue W(0); h-tile ----
#pragma unroll
  for (int i = 0; i < 4; ++i) {
    const int j = wv * 4 + i;
    gload_lds16(fragW + (size_t)j * 512 + l * 8, pool + 16384 + j * 1024);
  }
  // h tile bf16 @pool[0..16K): row*512 + ((col>>3)^(row&15))*16 + (col&7)*2
#pragma unroll
  for (int mi = 0; mi < 2; ++mi)
#pragma unroll
    for (int rr = 0; rr < 4; ++rr) {
      const int row = mi * 16 + (l >> 4) * 4 + rr;
#pragma unroll
      for (int ntl = 0; ntl < 4; ++ntl) {
        const int col = wv * 64 + ntl * 16 + (l & 15);
        const int ls = (col >> 3) ^ (row & 15);
        *(u16*)(pool + row * 512 + ls * 16 + (col & 7) * 2) = f2bf(acc[mi][ntl][rr]);
      }
    }
  asm volatile("s_waitcnt lgkmcnt(0)" ::: "memory");
  __builtin_amdgcn_s_barrier();

  f32x4 acc2[2][4] = {};
  for (int kt = 0; kt < 8; ++kt) {
    asm volatile("s_waitcnt vmcnt(0)" ::: "memory");     // W(kt) landed
    __builtin_amdgcn_s_barrier();
    __builtin_amdgcn_sched_barrier(0);
    if (kt < 7) {
      const u16* srcW = fragW + (size_t)(kt + 1) * 16 * 512;
      char* dstW = pool + 16384 + ((kt + 1) & 1) * 16384;
#pragma unroll
      for (int i = 0; i < 4; ++i) {
        const int j = wv * 4 + i;
        gload_lds16(srcW + (size_t)j * 512 + l * 8, dstW + j * 1024);
      }
    }
    __builtin_amdgcn_sched_barrier(0);
    const char* bW = pool + 16384 + (kt & 1) * 16384;
    short8 af[2];
#pragma unroll
    for (int mi = 0; mi < 2; ++mi) {
      const int row = mi * 16 + (l & 15);
      af[mi] = *(const short8*)(pool + row * 512 +
                                (((kt * 4 + (l >> 4)) ^ (row & 15)) << 4));
    }
#pragma unroll
    for (int ntl = 0; ntl < 4; ++ntl) {
      const short8 bfv = *(const short8*)(bW + (wv * 4 + ntl) * 1024 + l * 16);
#pragma unroll
      for (int mi = 0; mi < 2; ++mi)
        acc2[mi][ntl] = __builtin_amdgcn_mfma_f32_16x16x32_bf16(af[mi], bfv, acc2[mi][ntl], 0, 0, 0);
    }
    asm volatile("s_waitcnt lgkmcnt(0)" ::: "memory");
    __builtin_amdgcn_s_barrier();
  }

  // ---- bias + relu + LN + store (verbatim, proven) ----
  float bv[4], gg[4], bb[4];
#pragma unroll
  for (int ntl = 0; ntl < 4; ++ntl) {
    const int col = wv * 64 + ntl * 16 + (l & 15);
    bv[ntl] = b1[col]; gg[ntl] = gmm[col]; bb[ntl] = bta[col];
  }
  float* lnred = (float*)(pool + 49152);   // [4 wv][32 rows][2]
#pragma unroll
  for (int mi = 0; mi < 2; ++mi)
#pragma unroll
    for (int rr = 0; rr < 4; ++rr) {
      float s = 0.f, q = 0.f;
#pragma unroll
      for (int ntl = 0; ntl < 4; ++ntl) {
        const float v = fmaxf(acc2[mi][ntl][rr] + bv[ntl], 0.f);
        acc2[mi][ntl][rr] = v; s += v; q += v * v;
      }
#pragma unroll
      for (int m = 1; m < 16; m <<= 1) { s += __shfl_xor(s, m); q += __shfl_xor(q, m); }
      if ((l & 15) == 0) {
        const int row = mi * 16 + (l >> 4) * 4 + rr;
        lnred[(wv * 32 + row) * 2 + 0] = s;
        lnred[(wv * 32 + row) * 2 + 1] = q;
      }
    }
  __syncthreads();
#pragma unroll
  for (int mi = 0; mi < 2; ++mi)
#pragma unroll
    for (int rr = 0; rr < 4; ++rr) {
      const int row = mi * 16 + (l >> 4) * 4 + rr;
      float S = 0.f, Q = 0.f;
#pragma unroll
      for (int w2 = 0; w2 < 4; ++w2) {
        S += lnred[(w2 * 32 + row) * 2 + 0];
        Q += lnred[(w2 * 32 + row) * 2 + 1];
      }
      const float mu = S * (1.0f / 256.0f);
      const float rstd = rsqrtf(Q * (1.0f / 256.0f) - mu * mu + LN_EPS);
      float* op = out + (size_t)(m0 + row) * H_DIM;
#pragma unroll
      for (int ntl = 0; ntl < 4; ++ntl) {
        const int col = wv * 64 + ntl * 16 + (l & 15);
        op[col] = gg[ntl] * (acc2[mi][ntl][rr] - mu) * rstd + bb[ntl];
      }
    }
}

extern "C" void kernel_launch(void* const* d_in, const int* in_sizes, int n_in,
                              void* d_out, int out_size, void* d_ws, size_t ws_size,
                              hipStream_t stream) {
  const float* x    = (const float*)d_in[0];
  const float* emb  = (const float*)d_in[1];
  const float* W1   = (const float*)d_in[2];
  const float* b1   = (const float*)d_in[3];
  const float* gmm  = (const float*)d_in[4];
  const float* bta  = (const float*)d_in[5];
  const int*   gidx = (const int*)d_in[6];
  float* out = (float*)d_out;

  char* ws = (char*)d_ws;
  u16* fragB = (u16*)ws;                                   // [128 ksteps][16 nt][64][8] = 2 MB
  u16* fragW = (u16*)(ws + (size_t)H_DIM * L_DIM * 2);     // [8 ksteps][16 nt][64][8] = 128 KB

  prep_frag<<<512, 256, 0, stream>>>(emb, gidx, fragB);    // 2048 frags
  prep_frag<<<32, 256, 0, stream>>>(W1, nullptr, fragW);   // 128 frags
  fused<<<512, 256, 0, stream>>>(x, fragB, fragW, b1, gmm, bta, out);
}